// Round 1
// baseline (201.871 us; speedup 1.0000x reference)
//
#include <hip/hip_runtime.h>

#define TT 8192
#define DD 512
#define EE 32
#define HH 128

typedef float f32x4 __attribute__((ext_vector_type(4)));
typedef __bf16 bf16x8 __attribute__((ext_vector_type(8)));

__device__ __forceinline__ unsigned short f2bf(float f) {
  unsigned int u = __builtin_bit_cast(unsigned int, f);
  u = (u + 0x7FFFu + ((u >> 16) & 1u)) >> 16;
  return (unsigned short)u;
}

// keys [E][D][H] f32 -> keysT [E][H][D] bf16 ; values [E][H][D] f32 -> valuesT [E][D][H] bf16
__global__ __launch_bounds__(256) void convert_kernel(const float* __restrict__ keys,
                                                      const float* __restrict__ values,
                                                      unsigned short* __restrict__ keysT,
                                                      unsigned short* __restrict__ valuesT) {
  int idx = blockIdx.x * 256 + threadIdx.x;
  const int NK = EE * DD * HH; // 2M
  if (idx < NK) {
    int k = idx & (DD - 1);
    int n = (idx >> 9) & (HH - 1);
    int e = idx >> 16;
    keysT[idx] = f2bf(keys[((size_t)e * DD + k) * HH + n]);
  } else {
    int o = idx - NK;
    int k = o & (HH - 1);
    int n = (o >> 7) & (DD - 1);
    int e = o >> 16;
    valuesT[o] = f2bf(values[((size_t)e * HH + k) * DD + n]);
  }
}

// fp32 router: logits = x @ esel^T, top-2, sigmoid, scatter into per-expert lists.
// Also writes bf16 copy of x.
__global__ __launch_bounds__(256) void router_kernel(
    const float* __restrict__ x, const float* __restrict__ esel,
    unsigned short* __restrict__ xb, int* __restrict__ etok,
    float* __restrict__ ew, int* __restrict__ cur) {
  __shared__ float xs[64][68];
  __shared__ float ss[32][68];
  __shared__ float ls[64][33];
  __shared__ int bcnt[EE], bbase[EE], bcur[EE];
  const int tid = threadIdx.x;
  const int tok0 = blockIdx.x * 64;
  const int tx = tid & 15, ty = tid >> 4;

  float acc[4][2];
#pragma unroll
  for (int i = 0; i < 4; i++) { acc[i][0] = 0.f; acc[i][1] = 0.f; }

  for (int ks = 0; ks < DD; ks += 64) {
#pragma unroll
    for (int i = 0; i < 4; i++) {
      int f = tid + i * 256;
      int r = f >> 4, c4 = f & 15;
      float4 v = *(const float4*)&x[(size_t)(tok0 + r) * DD + ks + c4 * 4];
      *(float4*)&xs[r][c4 * 4] = v;
      ushort4 b;
      b.x = f2bf(v.x); b.y = f2bf(v.y); b.z = f2bf(v.z); b.w = f2bf(v.w);
      *(ushort4*)&xb[(size_t)(tok0 + r) * DD + ks + c4 * 4] = b;
    }
#pragma unroll
    for (int i = 0; i < 2; i++) {
      int f = tid + i * 256;
      int r = f >> 4, c4 = f & 15;
      *(float4*)&ss[r][c4 * 4] = *(const float4*)&esel[(size_t)r * DD + ks + c4 * 4];
    }
    __syncthreads();
#pragma unroll
    for (int k4 = 0; k4 < 16; k4++) {
      float4 b0 = *(const float4*)&ss[tx][k4 * 4];
      float4 b1 = *(const float4*)&ss[tx + 16][k4 * 4];
#pragma unroll
      for (int i = 0; i < 4; i++) {
        float4 a = *(const float4*)&xs[ty * 4 + i][k4 * 4];
        acc[i][0] += a.x * b0.x + a.y * b0.y + a.z * b0.z + a.w * b0.w;
        acc[i][1] += a.x * b1.x + a.y * b1.y + a.z * b1.z + a.w * b1.w;
      }
    }
    __syncthreads();
  }

#pragma unroll
  for (int i = 0; i < 4; i++) {
    ls[ty * 4 + i][tx] = acc[i][0];
    ls[ty * 4 + i][tx + 16] = acc[i][1];
  }
  if (tid < EE) bcnt[tid] = 0;
  __syncthreads();

  int i0 = 0, i1 = 0;
  float w0 = 0.f, w1 = 0.f;
  if (tid < 64) {
    float m0 = -3.4e38f;
#pragma unroll
    for (int e2 = 0; e2 < EE; e2++) {
      float v = ls[tid][e2];
      if (v > m0) { m0 = v; i0 = e2; }
    }
    float m1 = -3.4e38f;
    i1 = (i0 == 0) ? 1 : 0;
#pragma unroll
    for (int e2 = 0; e2 < EE; e2++) {
      float v = ls[tid][e2];
      if (e2 != i0 && v > m1) { m1 = v; i1 = e2; }
    }
    w0 = 1.f / (1.f + expf(-m0));
    w1 = 1.f / (1.f + expf(-m1));
    atomicAdd(&bcnt[i0], 1);
    atomicAdd(&bcnt[i1], 1);
  }
  __syncthreads();
  if (tid < EE) { bbase[tid] = atomicAdd(&cur[tid], bcnt[tid]); bcur[tid] = 0; }
  __syncthreads();
  if (tid < 64) {
    int t = tok0 + tid;
    int p0 = bbase[i0] + atomicAdd(&bcur[i0], 1);
    etok[(size_t)i0 * TT + p0] = t;
    ew[(size_t)i0 * TT + p0] = w0;
    int p1 = bbase[i1] + atomicAdd(&bcur[i1], 1);
    etok[(size_t)i1 * TT + p1] = t;
    ew[(size_t)i1 * TT + p1] = w1;
  }
}

// Grouped expert GEMM: per (expert, 64-token tile): h=relu(Xg@K_e) then out += w*(h@V_e)
__global__ __launch_bounds__(256) void moe_gemm_kernel(
    const unsigned short* __restrict__ xb,
    const unsigned short* __restrict__ keysT,
    const unsigned short* __restrict__ valuesT,
    const int* __restrict__ cur,
    const int* __restrict__ etok,
    const float* __restrict__ ew,
    float* __restrict__ out) {
  const int e = blockIdx.x;
  const int cnt = cur[e];
  const int base = blockIdx.y * 64;
  if (base >= cnt) return;

  __shared__ int tok_s[64];
  __shared__ float w_s[64];
  __shared__ unsigned short h_lds[64][136];

  const int tid = threadIdx.x;
  if (tid < 64) {
    int i = base + tid;
    if (i < cnt) {
      tok_s[tid] = etok[(size_t)e * TT + i];
      w_s[tid] = ew[(size_t)e * TT + i];
    } else {
      tok_s[tid] = etok[(size_t)e * TT + base];  // clamp to a valid row
      w_s[tid] = 0.f;                            // zero weight -> exact no-op add
    }
  }
  __syncthreads();
  const int wv = tid >> 6, lane = tid & 63;
  const int lh = lane >> 4, ll = lane & 15;

  // ---- GEMM1: h[64][128] = relu(Xg[64][512] @ keysT^T) ----
  f32x4 acc[8];
#pragma unroll
  for (int n = 0; n < 8; n++) { acc[n][0] = 0.f; acc[n][1] = 0.f; acc[n][2] = 0.f; acc[n][3] = 0.f; }

  const unsigned short* kT = keysT + (size_t)e * HH * DD;
  const unsigned short* ap = xb + (size_t)tok_s[wv * 16 + ll] * DD + lh * 8;
#pragma unroll
  for (int kk = 0; kk < 16; kk++) {
    bf16x8 af = *(const bf16x8*)(ap + kk * 32);
#pragma unroll
    for (int nt = 0; nt < 8; nt++) {
      bf16x8 bfg = *(const bf16x8*)(kT + (size_t)(nt * 16 + ll) * DD + kk * 32 + lh * 8);
      acc[nt] = __builtin_amdgcn_mfma_f32_16x16x32_bf16(af, bfg, acc[nt], 0, 0, 0);
    }
  }
#pragma unroll
  for (int nt = 0; nt < 8; nt++) {
#pragma unroll
    for (int r = 0; r < 4; r++) {
      int row = wv * 16 + lh * 4 + r;
      h_lds[row][nt * 16 + ll] = f2bf(fmaxf(acc[nt][r], 0.f));
    }
  }
  __syncthreads();

  // ---- GEMM2: out[tok] += w * (h[64][128] @ valuesT^T) ----
  bf16x8 a2[4];
#pragma unroll
  for (int kk = 0; kk < 4; kk++)
    a2[kk] = *(const bf16x8*)&h_lds[wv * 16 + ll][kk * 32 + lh * 8];

  float wr[4];
  int tk[4];
#pragma unroll
  for (int r = 0; r < 4; r++) {
    int row = wv * 16 + lh * 4 + r;
    wr[r] = w_s[row];
    tk[r] = tok_s[row];
  }
  const unsigned short* vT = valuesT + (size_t)e * DD * HH;
  for (int nt = 0; nt < 32; nt++) {
    f32x4 c2;
    c2[0] = 0.f; c2[1] = 0.f; c2[2] = 0.f; c2[3] = 0.f;
#pragma unroll
    for (int kk = 0; kk < 4; kk++) {
      bf16x8 bfg = *(const bf16x8*)(vT + (size_t)(nt * 16 + ll) * HH + kk * 32 + lh * 8);
      c2 = __builtin_amdgcn_mfma_f32_16x16x32_bf16(a2[kk], bfg, c2, 0, 0, 0);
    }
    int col = nt * 16 + ll;
#pragma unroll
    for (int r = 0; r < 4; r++) {
      atomicAdd(&out[(size_t)tk[r] * DD + col], c2[r] * wr[r]);
    }
  }
}

extern "C" void kernel_launch(void* const* d_in, const int* in_sizes, int n_in,
                              void* d_out, int out_size, void* d_ws, size_t ws_size,
                              hipStream_t stream) {
  const float* x = (const float*)d_in[0];
  const float* esel = (const float*)d_in[1];
  const float* keys = (const float*)d_in[2];
  const float* values = (const float*)d_in[3];
  float* out = (float*)d_out;

  char* p = (char*)d_ws;
  unsigned short* xb = (unsigned short*)p;      p += (size_t)TT * DD * 2;
  unsigned short* keysT = (unsigned short*)p;   p += (size_t)EE * DD * HH * 2;
  unsigned short* valuesT = (unsigned short*)p; p += (size_t)EE * DD * HH * 2;
  int* cur = (int*)p;                           p += 256;
  int* etok = (int*)p;                          p += (size_t)EE * TT * 4;
  float* ew = (float*)p;                        p += (size_t)EE * TT * 4;

  hipMemsetAsync(cur, 0, EE * 4, stream);
  hipMemsetAsync(out, 0, (size_t)out_size * 4, stream);
  convert_kernel<<<(EE * DD * HH * 2) / 256, 256, 0, stream>>>(keys, values, keysT, valuesT);
  router_kernel<<<TT / 64, 256, 0, stream>>>(x, esel, xb, etok, ew, cur);
  moe_gemm_kernel<<<dim3(EE, TT / 64), 256, 0, stream>>>(xb, keysT, valuesT, cur, etok, ew, out);
}

// Round 2
// 159.691 us; speedup vs baseline: 1.2641x; 1.2641x over previous
//
#include <hip/hip_runtime.h>

#define TT 8192
#define DD 512
#define EE 32
#define HH 128

typedef float f32x4 __attribute__((ext_vector_type(4)));
typedef __bf16 bf16x8 __attribute__((ext_vector_type(8)));

__device__ __forceinline__ unsigned short f2bf(float f) {
  unsigned int u = __builtin_bit_cast(unsigned int, f);
  u = (u + 0x7FFFu + ((u >> 16) & 1u)) >> 16;
  return (unsigned short)u;
}

#define GLD16(g, l)                                                            \
  __builtin_amdgcn_global_load_lds(                                            \
      (const __attribute__((address_space(1))) unsigned int*)(g),              \
      (__attribute__((address_space(3))) unsigned int*)(l), 16, 0, 0)

// LDS-tiled transpose+convert:
// keys [E][D][H] f32 -> keysT [E][H][D] bf16 ; values [E][H][D] f32 -> valuesT [E][D][H] bf16
__global__ __launch_bounds__(256) void convert_kernel(const float* __restrict__ keys,
                                                      const float* __restrict__ values,
                                                      unsigned short* __restrict__ keysT,
                                                      unsigned short* __restrict__ valuesT) {
  __shared__ float tile[64][68];  // 68 floats = 272B rows (16B aligned), 2-way-max read
  int bid = blockIdx.x;
  const float* src;
  unsigned short* dst;
  int R, C, r0, c0, e;
  if (bid < 512) {
    e = bid >> 4; int sub = bid & 15;
    R = DD; C = HH; r0 = (sub >> 1) * 64; c0 = (sub & 1) * 64;
    src = keys; dst = keysT;
  } else {
    bid -= 512;
    e = bid >> 4; int sub = bid & 15;
    R = HH; C = DD; r0 = (sub & 1) * 64; c0 = (sub >> 1) * 64;
    src = values; dst = valuesT;
  }
  const int t = threadIdx.x;
  const int rl = t >> 2, cq = (t & 3) * 16;
  const float* s0 = src + ((size_t)e * R + r0 + rl) * C + c0 + cq;
#pragma unroll
  for (int i = 0; i < 4; i++) *(float4*)&tile[rl][cq + 4 * i] = *(const float4*)(s0 + 4 * i);
  __syncthreads();
  // out row (C-dim) = c0 + rl ; cols (R-dim) r0+cq..+16
  unsigned short* d0 = dst + ((size_t)e * C + c0 + rl) * R + r0 + cq;
#pragma unroll
  for (int i = 0; i < 4; i++) {
    ushort4 v;
    v.x = f2bf(tile[cq + 4 * i + 0][rl]);
    v.y = f2bf(tile[cq + 4 * i + 1][rl]);
    v.z = f2bf(tile[cq + 4 * i + 2][rl]);
    v.w = f2bf(tile[cq + 4 * i + 3][rl]);
    *(ushort4*)(d0 + 4 * i) = v;
  }
}

// fp32 router: logits = x @ esel^T, top-2, sigmoid, scatter into per-expert lists.
// Also writes bf16 copy of x.
__global__ __launch_bounds__(256) void router_kernel(
    const float* __restrict__ x, const float* __restrict__ esel,
    unsigned short* __restrict__ xb, int* __restrict__ etok,
    float* __restrict__ ew, int* __restrict__ cur) {
  __shared__ float xs[64][68];
  __shared__ float ss[32][68];
  __shared__ float ls[64][33];
  __shared__ int bcnt[EE], bbase[EE], bcur[EE];
  const int tid = threadIdx.x;
  const int tok0 = blockIdx.x * 64;
  const int tx = tid & 15, ty = tid >> 4;

  float acc[4][2];
#pragma unroll
  for (int i = 0; i < 4; i++) { acc[i][0] = 0.f; acc[i][1] = 0.f; }

  for (int ks = 0; ks < DD; ks += 64) {
#pragma unroll
    for (int i = 0; i < 4; i++) {
      int f = tid + i * 256;
      int r = f >> 4, c4 = f & 15;
      float4 v = *(const float4*)&x[(size_t)(tok0 + r) * DD + ks + c4 * 4];
      *(float4*)&xs[r][c4 * 4] = v;
      ushort4 b;
      b.x = f2bf(v.x); b.y = f2bf(v.y); b.z = f2bf(v.z); b.w = f2bf(v.w);
      *(ushort4*)&xb[(size_t)(tok0 + r) * DD + ks + c4 * 4] = b;
    }
#pragma unroll
    for (int i = 0; i < 2; i++) {
      int f = tid + i * 256;
      int r = f >> 4, c4 = f & 15;
      *(float4*)&ss[r][c4 * 4] = *(const float4*)&esel[(size_t)r * DD + ks + c4 * 4];
    }
    __syncthreads();
#pragma unroll
    for (int k4 = 0; k4 < 16; k4++) {
      float4 b0 = *(const float4*)&ss[tx][k4 * 4];
      float4 b1 = *(const float4*)&ss[tx + 16][k4 * 4];
#pragma unroll
      for (int i = 0; i < 4; i++) {
        float4 a = *(const float4*)&xs[ty * 4 + i][k4 * 4];
        acc[i][0] += a.x * b0.x + a.y * b0.y + a.z * b0.z + a.w * b0.w;
        acc[i][1] += a.x * b1.x + a.y * b1.y + a.z * b1.z + a.w * b1.w;
      }
    }
    __syncthreads();
  }

#pragma unroll
  for (int i = 0; i < 4; i++) {
    ls[ty * 4 + i][tx] = acc[i][0];
    ls[ty * 4 + i][tx + 16] = acc[i][1];
  }
  if (tid < EE) bcnt[tid] = 0;
  __syncthreads();

  int i0 = 0, i1 = 0;
  float w0 = 0.f, w1 = 0.f;
  if (tid < 64) {
    float m0 = -3.4e38f;
#pragma unroll
    for (int e2 = 0; e2 < EE; e2++) {
      float v = ls[tid][e2];
      if (v > m0) { m0 = v; i0 = e2; }
    }
    float m1 = -3.4e38f;
    i1 = (i0 == 0) ? 1 : 0;
#pragma unroll
    for (int e2 = 0; e2 < EE; e2++) {
      float v = ls[tid][e2];
      if (e2 != i0 && v > m1) { m1 = v; i1 = e2; }
    }
    w0 = 1.f / (1.f + expf(-m0));
    w1 = 1.f / (1.f + expf(-m1));
    atomicAdd(&bcnt[i0], 1);
    atomicAdd(&bcnt[i1], 1);
  }
  __syncthreads();
  if (tid < EE) { bbase[tid] = atomicAdd(&cur[tid], bcnt[tid]); bcur[tid] = 0; }
  __syncthreads();
  if (tid < 64) {
    int t = tok0 + tid;
    int p0 = bbase[i0] + atomicAdd(&bcur[i0], 1);
    etok[(size_t)i0 * TT + p0] = t;
    ew[(size_t)i0 * TT + p0] = w0;
    int p1 = bbase[i1] + atomicAdd(&bcur[i1], 1);
    etok[(size_t)i1 * TT + p1] = t;
    ew[(size_t)i1 * TT + p1] = w1;
  }
}

// Grouped expert GEMM, LDS-staged B with double buffer + XOR swizzle.
// Per (expert, 64-token tile): h=relu(Xg@K_e) then out += w*(h@V_e)
__global__ __launch_bounds__(256) void moe_gemm_kernel(
    const unsigned short* __restrict__ xb,
    const unsigned short* __restrict__ keysT,
    const unsigned short* __restrict__ valuesT,
    const int* __restrict__ cur,
    const int* __restrict__ etok,
    const float* __restrict__ ew,
    float* __restrict__ out) {
  const int e = blockIdx.x;
  const int cnt = cur[e];
  const int base = blockIdx.y * 64;
  if (base >= cnt) return;

  __shared__ unsigned short stage_buf[2][8192];  // 16KB each, linear dest for global_load_lds
  __shared__ unsigned short h_swz[8192];         // 64x128 bf16, XOR-swizzled, 16KB
  __shared__ int tok_s[64];
  __shared__ float w_s[64];

  const int tid = threadIdx.x;
  const int wv = tid >> 6, lane = tid & 63;
  const int ll = lane & 15, lh = lane >> 4;

  const unsigned short* kT = keysT + (size_t)e * HH * DD;
  const unsigned short* vT = valuesT + (size_t)e * DD * HH;

  // B1 chunk c: keysT rows n=0..127, cols c*64..+64 -> LDS [128][64] linear rows,
  // source pre-swizzled so reads at byte n*128 + (colbyte ^ ((n&7)<<4)) are correct.
  auto stage_b1 = [&](int c, int b) {
#pragma unroll
    for (int i = 0; i < 4; i++) {
      int P = (i * 256 + tid) * 16;
      int n = P >> 7;
      int q = P & 127;
      const char* g = (const char*)(kT + (size_t)n * DD + c * 64) + (q ^ ((n & 7) << 4));
      char* l = (char*)stage_buf[b] + (i * 256 + wv * 64) * 16;  // wave-uniform base
      GLD16(g, l);
    }
  };
  // B2 chunk c: valuesT rows n=c*64..+64, all 128 cols -> LDS [64][128] linear rows.
  auto stage_b2 = [&](int c, int b) {
#pragma unroll
    for (int i = 0; i < 4; i++) {
      int P = (i * 256 + tid) * 16;
      int r = P >> 8;
      int q = P & 255;
      const char* g = (const char*)(vT + (size_t)(c * 64 + r) * HH) + (q ^ ((r & 7) << 4));
      char* l = (char*)stage_buf[b] + (i * 256 + wv * 64) * 16;
      GLD16(g, l);
    }
  };

  stage_b1(0, 0);
  if (tid < 64) {
    int i = base + tid;
    if (i < cnt) {
      tok_s[tid] = etok[(size_t)e * TT + i];
      w_s[tid] = ew[(size_t)e * TT + i];
    } else {
      tok_s[tid] = etok[(size_t)e * TT + base];  // clamp to valid row
      w_s[tid] = 0.f;                            // zero weight -> exact no-op add
    }
  }
  __syncthreads();

  const unsigned short* ap = xb + (size_t)tok_s[wv * 16 + ll] * DD;

  // ---- GEMM1: h[64][128] = relu(Xg[64][512] @ K_e) ----
  f32x4 acc[8];
#pragma unroll
  for (int n = 0; n < 8; n++) { acc[n][0] = 0.f; acc[n][1] = 0.f; acc[n][2] = 0.f; acc[n][3] = 0.f; }

  for (int c = 0; c < 8; c++) {
    if (c < 7) stage_b1(c + 1, (c + 1) & 1);
    else       stage_b2(0, 0);
    const char* sb = (const char*)stage_buf[c & 1];
#pragma unroll
    for (int kkl = 0; kkl < 2; kkl++) {
      bf16x8 af = *(const bf16x8*)(ap + c * 64 + kkl * 32 + lh * 8);
#pragma unroll
      for (int nt = 0; nt < 8; nt++) {
        int n = nt * 16 + ll;
        int boff = n * 128 + ((kkl * 64 + lh * 16) ^ ((n & 7) << 4));
        bf16x8 bfr = *(const bf16x8*)(sb + boff);
        acc[nt] = __builtin_amdgcn_mfma_f32_16x16x32_bf16(af, bfr, acc[nt], 0, 0, 0);
      }
    }
    __syncthreads();
  }

  // h -> LDS (swizzled). Rows are wave-private: no barrier needed before re-read.
#pragma unroll
  for (int nt = 0; nt < 8; nt++) {
#pragma unroll
    for (int r = 0; r < 4; r++) {
      int row = wv * 16 + lh * 4 + r;
      int col = nt * 16 + ll;
      int off = row * 256 + ((col * 2) ^ ((row & 7) << 4));
      *(unsigned short*)((char*)h_swz + off) = f2bf(fmaxf(acc[nt][r], 0.f));
    }
  }
  bf16x8 a2[4];
#pragma unroll
  for (int kk = 0; kk < 4; kk++) {
    int row = wv * 16 + ll;
    int off = row * 256 + ((kk * 64 + lh * 16) ^ ((row & 7) << 4));
    a2[kk] = *(const bf16x8*)((const char*)h_swz + off);
  }

  float wr[4];
  int tk[4];
#pragma unroll
  for (int r = 0; r < 4; r++) {
    int row = wv * 16 + lh * 4 + r;
    wr[r] = w_s[row];
    tk[r] = tok_s[row];
  }

  // ---- GEMM2: out[tok] += w * (h @ V_e), N processed in 8 chunks of 64 cols ----
  for (int c = 0; c < 8; c++) {
    if (c < 7) stage_b2(c + 1, (c + 1) & 1);
    const char* sb = (const char*)stage_buf[c & 1];
#pragma unroll
    for (int ntl = 0; ntl < 4; ntl++) {
      f32x4 c2;
      c2[0] = 0.f; c2[1] = 0.f; c2[2] = 0.f; c2[3] = 0.f;
#pragma unroll
      for (int kk = 0; kk < 4; kk++) {
        int r = ntl * 16 + ll;
        int boff = r * 256 + ((kk * 64 + lh * 16) ^ ((r & 7) << 4));
        bf16x8 bfr = *(const bf16x8*)(sb + boff);
        c2 = __builtin_amdgcn_mfma_f32_16x16x32_bf16(a2[kk], bfr, c2, 0, 0, 0);
      }
      int col = c * 64 + ntl * 16 + ll;
#pragma unroll
      for (int r = 0; r < 4; r++) {
        atomicAdd(&out[(size_t)tk[r] * DD + col], c2[r] * wr[r]);
      }
    }
    __syncthreads();
  }
}

extern "C" void kernel_launch(void* const* d_in, const int* in_sizes, int n_in,
                              void* d_out, int out_size, void* d_ws, size_t ws_size,
                              hipStream_t stream) {
  const float* x = (const float*)d_in[0];
  const float* esel = (const float*)d_in[1];
  const float* keys = (const float*)d_in[2];
  const float* values = (const float*)d_in[3];
  float* out = (float*)d_out;

  char* p = (char*)d_ws;
  unsigned short* xb = (unsigned short*)p;      p += (size_t)TT * DD * 2;
  unsigned short* keysT = (unsigned short*)p;   p += (size_t)EE * DD * HH * 2;
  unsigned short* valuesT = (unsigned short*)p; p += (size_t)EE * DD * HH * 2;
  int* cur = (int*)p;                           p += 256;
  int* etok = (int*)p;                          p += (size_t)EE * TT * 4;
  float* ew = (float*)p;                        p += (size_t)EE * TT * 4;

  hipMemsetAsync(cur, 0, EE * 4, stream);
  hipMemsetAsync(out, 0, (size_t)out_size * 4, stream);
  convert_kernel<<<1024, 256, 0, stream>>>(keys, values, keysT, valuesT);
  router_kernel<<<TT / 64, 256, 0, stream>>>(x, esel, xb, etok, ew, cur);
  moe_gemm_kernel<<<dim3(EE, TT / 64), 256, 0, stream>>>(xb, keysT, valuesT, cur, etok, ew, out);
}

// Round 3
// 78.541 us; speedup vs baseline: 2.5703x; 2.0332x over previous
//
#include <hip/hip_runtime.h>

#define TT 8192
#define DD 512
#define EE 32
#define HH 128

typedef float f32x4 __attribute__((ext_vector_type(4)));
typedef __bf16 bf16x8 __attribute__((ext_vector_type(8)));

__device__ __forceinline__ unsigned short f2bf(float f) {
  unsigned int u = __builtin_bit_cast(unsigned int, f);
  u = (u + 0x7FFFu + ((u >> 16) & 1u)) >> 16;
  return (unsigned short)u;
}

#define GLD16(g, l)                                                            \
  __builtin_amdgcn_global_load_lds(                                            \
      (const __attribute__((address_space(1))) unsigned int*)(g),              \
      (__attribute__((address_space(3))) unsigned int*)(l), 16, 0, 0)

// LDS-tiled transpose+convert:
// keys [E][D][H] f32 -> keysT [E][H][D] bf16 ; values [E][H][D] f32 -> valuesT [E][D][H] bf16
__global__ __launch_bounds__(256) void convert_kernel(const float* __restrict__ keys,
                                                      const float* __restrict__ values,
                                                      unsigned short* __restrict__ keysT,
                                                      unsigned short* __restrict__ valuesT) {
  __shared__ float tile[64][68];
  int bid = blockIdx.x;
  const float* src;
  unsigned short* dst;
  int R, C, r0, c0, e;
  if (bid < 512) {
    e = bid >> 4; int sub = bid & 15;
    R = DD; C = HH; r0 = (sub >> 1) * 64; c0 = (sub & 1) * 64;
    src = keys; dst = keysT;
  } else {
    bid -= 512;
    e = bid >> 4; int sub = bid & 15;
    R = HH; C = DD; r0 = (sub & 1) * 64; c0 = (sub >> 1) * 64;
    src = values; dst = valuesT;
  }
  const int t = threadIdx.x;
  const int rl = t >> 2, cq = (t & 3) * 16;
  const float* s0 = src + ((size_t)e * R + r0 + rl) * C + c0 + cq;
#pragma unroll
  for (int i = 0; i < 4; i++) *(float4*)&tile[rl][cq + 4 * i] = *(const float4*)(s0 + 4 * i);
  __syncthreads();
  unsigned short* d0 = dst + ((size_t)e * C + c0 + rl) * R + r0 + cq;
#pragma unroll
  for (int i = 0; i < 4; i++) {
    ushort4 v;
    v.x = f2bf(tile[cq + 4 * i + 0][rl]);
    v.y = f2bf(tile[cq + 4 * i + 1][rl]);
    v.z = f2bf(tile[cq + 4 * i + 2][rl]);
    v.w = f2bf(tile[cq + 4 * i + 3][rl]);
    *(ushort4*)(d0 + 4 * i) = v;
  }
}

// fp32 router: logits = x @ esel^T, top-2, sigmoid, scatter into per-expert lists.
// List entry packs token | (slot<<20). Also writes bf16 copy of x.
__global__ __launch_bounds__(256) void router_kernel(
    const float* __restrict__ x, const float* __restrict__ esel,
    unsigned short* __restrict__ xb, int* __restrict__ etok,
    float* __restrict__ ew, int* __restrict__ cur) {
  __shared__ float xs[64][68];
  __shared__ float ss[32][68];
  __shared__ float ls[64][33];
  __shared__ int bcnt[EE], bbase[EE], bcur[EE];
  const int tid = threadIdx.x;
  const int tok0 = blockIdx.x * 64;
  const int tx = tid & 15, ty = tid >> 4;

  float acc[4][2];
#pragma unroll
  for (int i = 0; i < 4; i++) { acc[i][0] = 0.f; acc[i][1] = 0.f; }

  for (int ks = 0; ks < DD; ks += 64) {
#pragma unroll
    for (int i = 0; i < 4; i++) {
      int f = tid + i * 256;
      int r = f >> 4, c4 = f & 15;
      float4 v = *(const float4*)&x[(size_t)(tok0 + r) * DD + ks + c4 * 4];
      *(float4*)&xs[r][c4 * 4] = v;
      ushort4 b;
      b.x = f2bf(v.x); b.y = f2bf(v.y); b.z = f2bf(v.z); b.w = f2bf(v.w);
      *(ushort4*)&xb[(size_t)(tok0 + r) * DD + ks + c4 * 4] = b;
    }
#pragma unroll
    for (int i = 0; i < 2; i++) {
      int f = tid + i * 256;
      int r = f >> 4, c4 = f & 15;
      *(float4*)&ss[r][c4 * 4] = *(const float4*)&esel[(size_t)r * DD + ks + c4 * 4];
    }
    __syncthreads();
#pragma unroll
    for (int k4 = 0; k4 < 16; k4++) {
      float4 b0 = *(const float4*)&ss[tx][k4 * 4];
      float4 b1 = *(const float4*)&ss[tx + 16][k4 * 4];
#pragma unroll
      for (int i = 0; i < 4; i++) {
        float4 a = *(const float4*)&xs[ty * 4 + i][k4 * 4];
        acc[i][0] += a.x * b0.x + a.y * b0.y + a.z * b0.z + a.w * b0.w;
        acc[i][1] += a.x * b1.x + a.y * b1.y + a.z * b1.z + a.w * b1.w;
      }
    }
    __syncthreads();
  }

#pragma unroll
  for (int i = 0; i < 4; i++) {
    ls[ty * 4 + i][tx] = acc[i][0];
    ls[ty * 4 + i][tx + 16] = acc[i][1];
  }
  if (tid < EE) bcnt[tid] = 0;
  __syncthreads();

  int i0 = 0, i1 = 0;
  float w0 = 0.f, w1 = 0.f;
  if (tid < 64) {
    float m0 = -3.4e38f;
#pragma unroll
    for (int e2 = 0; e2 < EE; e2++) {
      float v = ls[tid][e2];
      if (v > m0) { m0 = v; i0 = e2; }
    }
    float m1 = -3.4e38f;
    i1 = (i0 == 0) ? 1 : 0;
#pragma unroll
    for (int e2 = 0; e2 < EE; e2++) {
      float v = ls[tid][e2];
      if (e2 != i0 && v > m1) { m1 = v; i1 = e2; }
    }
    w0 = 1.f / (1.f + expf(-m0));
    w1 = 1.f / (1.f + expf(-m1));
    atomicAdd(&bcnt[i0], 1);
    atomicAdd(&bcnt[i1], 1);
  }
  __syncthreads();
  if (tid < EE) { bbase[tid] = atomicAdd(&cur[tid], bcnt[tid]); bcur[tid] = 0; }
  __syncthreads();
  if (tid < 64) {
    int t = tok0 + tid;
    int p0 = bbase[i0] + atomicAdd(&bcur[i0], 1);
    etok[(size_t)i0 * TT + p0] = t;              // slot 0
    ew[(size_t)i0 * TT + p0] = w0;
    int p1 = bbase[i1] + atomicAdd(&bcur[i1], 1);
    etok[(size_t)i1 * TT + p1] = t | (1 << 20);  // slot 1
    ew[(size_t)i1 * TT + p1] = w1;
  }
}

// Grouped expert GEMM, 8 waves, LDS-staged B (double buffer + XOR swizzle).
// Per (expert, 64-token tile): h=relu(Xg@K_e); ybuf[slot][tok] = w*(h@V_e) (plain stores).
__global__ __launch_bounds__(512) void moe_gemm_kernel(
    const unsigned short* __restrict__ xb,
    const unsigned short* __restrict__ keysT,
    const unsigned short* __restrict__ valuesT,
    const int* __restrict__ cur,
    const int* __restrict__ etok,
    const float* __restrict__ ew,
    float* __restrict__ ybuf) {
  const int e = blockIdx.x;
  const int cnt = cur[e];
  const int base = blockIdx.y * 64;
  if (base >= cnt) return;

  __shared__ unsigned short stage_buf[2][8192];  // 16KB each, linear dest for global_load_lds
  __shared__ unsigned short h_swz[8192];         // 64x128 bf16, XOR-swizzled
  __shared__ int tok_s[64];
  __shared__ int srow_s[64];
  __shared__ float w_s[64];

  const int tid = threadIdx.x;
  const int lane = tid & 63;
  const int wv = tid >> 6;          // 0..7
  const int wm = wv & 3;            // row group (16 rows each)
  const int wn = wv >> 2;           // N half
  const int ll = lane & 15, lh = lane >> 4;

  const unsigned short* kT = keysT + (size_t)e * HH * DD;
  const unsigned short* vT = valuesT + (size_t)e * DD * HH;

  // B1 chunk c: keysT rows n=0..127, k-cols c*64..+64 -> LDS [128 rows][128B], src pre-swizzled.
  auto stage_b1 = [&](int c, int b) {
#pragma unroll
    for (int i = 0; i < 2; i++) {
      int P = (i * 512 + tid) * 16;
      int n = P >> 7;
      int q = P & 127;
      const char* g = (const char*)(kT + (size_t)n * DD + c * 64) + (q ^ ((n & 7) << 4));
      char* l = (char*)stage_buf[b] + (i * 512 + (tid & ~63)) * 16;  // wave-uniform base
      GLD16(g, l);
    }
  };
  // B2 chunk c: valuesT rows n=c*64..+64 (out cols), all 128 k -> LDS [64 rows][256B].
  auto stage_b2 = [&](int c, int b) {
#pragma unroll
    for (int i = 0; i < 2; i++) {
      int P = (i * 512 + tid) * 16;
      int r = P >> 8;
      int q = P & 255;
      const char* g = (const char*)(vT + (size_t)(c * 64 + r) * HH) + (q ^ ((r & 7) << 4));
      char* l = (char*)stage_buf[b] + (i * 512 + (tid & ~63)) * 16;
      GLD16(g, l);
    }
  };

  stage_b1(0, 0);
  if (tid < 64) {
    int i = base + tid;
    if (i < cnt) {
      int v = etok[(size_t)e * TT + i];
      int t = v & 0xFFFFF;
      tok_s[tid] = t;
      srow_s[tid] = (v >> 20) * (TT + 1) + t;
      w_s[tid] = ew[(size_t)e * TT + i];
    } else {
      tok_s[tid] = etok[(size_t)e * TT + base] & 0xFFFFF;  // valid row for A-gather
      srow_s[tid] = TT;                                    // dump row (slot 0)
      w_s[tid] = 0.f;
    }
  }
  __syncthreads();

  const unsigned short* ap = xb + (size_t)tok_s[wm * 16 + ll] * DD;

  // ---- GEMM1: h[64][128] = relu(Xg[64][512] @ K_e); wave (wm,wn): rows wm*16+, cols wn*64+ ----
  f32x4 acc[4];
#pragma unroll
  for (int n = 0; n < 4; n++) { acc[n][0] = 0.f; acc[n][1] = 0.f; acc[n][2] = 0.f; acc[n][3] = 0.f; }

  for (int c = 0; c < 8; c++) {
    if (c < 7) stage_b1(c + 1, (c + 1) & 1);
    else       stage_b2(0, 0);
    const char* sb = (const char*)stage_buf[c & 1];
#pragma unroll
    for (int kkl = 0; kkl < 2; kkl++) {
      bf16x8 af = *(const bf16x8*)(ap + c * 64 + kkl * 32 + lh * 8);
#pragma unroll
      for (int nt = 0; nt < 4; nt++) {
        int n = wn * 64 + nt * 16 + ll;
        int boff = n * 128 + ((kkl * 64 + lh * 16) ^ ((n & 7) << 4));
        bf16x8 bfr = *(const bf16x8*)(sb + boff);
        acc[nt] = __builtin_amdgcn_mfma_f32_16x16x32_bf16(af, bfr, acc[nt], 0, 0, 0);
      }
    }
    __syncthreads();
  }

  // h -> LDS (swizzled); cross-wave (wn halves) so barrier after.
#pragma unroll
  for (int nt = 0; nt < 4; nt++) {
#pragma unroll
    for (int r = 0; r < 4; r++) {
      int row = wm * 16 + lh * 4 + r;
      int col = wn * 64 + nt * 16 + ll;
      int off = row * 256 + ((col * 2) ^ ((row & 7) << 4));
      *(unsigned short*)((char*)h_swz + off) = f2bf(fmaxf(acc[nt][r], 0.f));
    }
  }
  __syncthreads();

  bf16x8 a2[4];
#pragma unroll
  for (int kk = 0; kk < 4; kk++) {
    int row = wm * 16 + ll;
    int off = row * 256 + ((kk * 64 + lh * 16) ^ ((row & 7) << 4));
    a2[kk] = *(const bf16x8*)((const char*)h_swz + off);
  }

  float wr[4];
  int sr[4];
#pragma unroll
  for (int r = 0; r < 4; r++) {
    int row = wm * 16 + lh * 4 + r;
    wr[r] = w_s[row];
    sr[r] = srow_s[row];
  }

  // ---- GEMM2: ybuf[srow] = w * (h @ V_e); wave (wm,wn): rows wm*16+, col-sub wn*32+ ----
  for (int c = 0; c < 8; c++) {
    if (c < 7) stage_b2(c + 1, (c + 1) & 1);
    const char* sb = (const char*)stage_buf[c & 1];
#pragma unroll
    for (int ntl = 0; ntl < 2; ntl++) {
      f32x4 c2;
      c2[0] = 0.f; c2[1] = 0.f; c2[2] = 0.f; c2[3] = 0.f;
#pragma unroll
      for (int kk = 0; kk < 4; kk++) {
        int r = wn * 32 + ntl * 16 + ll;
        int boff = r * 256 + ((kk * 64 + lh * 16) ^ ((r & 7) << 4));
        bf16x8 bfr = *(const bf16x8*)(sb + boff);
        c2 = __builtin_amdgcn_mfma_f32_16x16x32_bf16(a2[kk], bfr, c2, 0, 0, 0);
      }
      int col = c * 64 + wn * 32 + ntl * 16 + ll;
#pragma unroll
      for (int r = 0; r < 4; r++) {
        ybuf[(size_t)sr[r] * DD + col] = c2[r] * wr[r];
      }
    }
    __syncthreads();
  }
}

// out[t][d] = ybuf[0][t][d] + ybuf[1][t][d]
__global__ __launch_bounds__(256) void combine_kernel(const float* __restrict__ ybuf,
                                                      float* __restrict__ out) {
  size_t i = ((size_t)blockIdx.x * 256 + threadIdx.x) * 4;
  float4 a = *(const float4*)(ybuf + i);
  float4 b = *(const float4*)(ybuf + (size_t)(TT + 1) * DD + i);
  float4 o;
  o.x = a.x + b.x; o.y = a.y + b.y; o.z = a.z + b.z; o.w = a.w + b.w;
  *(float4*)(out + i) = o;
}

extern "C" void kernel_launch(void* const* d_in, const int* in_sizes, int n_in,
                              void* d_out, int out_size, void* d_ws, size_t ws_size,
                              hipStream_t stream) {
  const float* x = (const float*)d_in[0];
  const float* esel = (const float*)d_in[1];
  const float* keys = (const float*)d_in[2];
  const float* values = (const float*)d_in[3];
  float* out = (float*)d_out;

  char* p = (char*)d_ws;
  unsigned short* xb = (unsigned short*)p;      p += (size_t)TT * DD * 2;
  unsigned short* keysT = (unsigned short*)p;   p += (size_t)EE * DD * HH * 2;
  unsigned short* valuesT = (unsigned short*)p; p += (size_t)EE * DD * HH * 2;
  int* cur = (int*)p;                           p += 256;
  int* etok = (int*)p;                          p += (size_t)EE * TT * 4;
  float* ew = (float*)p;                        p += (size_t)EE * TT * 4;
  float* ybuf = (float*)p;                      p += (size_t)2 * (TT + 1) * DD * 4;

  hipMemsetAsync(cur, 0, EE * 4, stream);
  convert_kernel<<<1024, 256, 0, stream>>>(keys, values, keysT, valuesT);
  router_kernel<<<TT / 64, 256, 0, stream>>>(x, esel, xb, etok, ew, cur);
  moe_gemm_kernel<<<dim3(EE, TT / 64), 512, 0, stream>>>(xb, keysT, valuesT, cur, etok, ew, ybuf);
  combine_kernel<<<(TT * DD / 4) / 256, 256, 0, stream>>>(ybuf, out);
}

// Round 4
// 62.563 us; speedup vs baseline: 3.2267x; 1.2554x over previous
//
#include <hip/hip_runtime.h>

#define TT 8192
#define DD 512
#define EE 32
#define HH 128

typedef float f32x4 __attribute__((ext_vector_type(4)));
typedef __bf16 bf16x8 __attribute__((ext_vector_type(8)));

__device__ __forceinline__ unsigned short f2bf(float f) {
  unsigned int u = __builtin_bit_cast(unsigned int, f);
  u = (u + 0x7FFFu + ((u >> 16) & 1u)) >> 16;
  return (unsigned short)u;
}
__device__ __forceinline__ float bf2f(unsigned short h) {
  return __builtin_bit_cast(float, (unsigned int)h << 16);
}

#define GLD16(g, l)                                                            \
  __builtin_amdgcn_global_load_lds(                                            \
      (const __attribute__((address_space(1))) unsigned int*)(g),              \
      (__attribute__((address_space(3))) unsigned int*)(l), 16, 0, 0)

// LDS-tiled transpose+convert for keys/values; bid 1024 converts esel to 3-way bf16 split.
__global__ __launch_bounds__(256) void convert_kernel(
    const float* __restrict__ keys, const float* __restrict__ values,
    const float* __restrict__ esel,
    unsigned short* __restrict__ keysT, unsigned short* __restrict__ valuesT,
    unsigned short* __restrict__ eselh, unsigned short* __restrict__ esell,
    unsigned short* __restrict__ esell2) {
  __shared__ float tile[64][68];
  int bid = blockIdx.x;
  if (bid == 1024) {
    // esel [32][512] fp32 -> hi/lo/lo2 bf16 (exact 24-bit reconstruction)
    const int t = threadIdx.x;
#pragma unroll
    for (int j = 0; j < 16; j++) {
      int i4 = (j * 256 + t) * 4;
      float4 v = *(const float4*)(esel + i4);
      float vv[4] = {v.x, v.y, v.z, v.w};
      ushort4 h, l, l2;
      unsigned short* hp = &h.x;
      unsigned short* lp = &l.x;
      unsigned short* l2p = &l2.x;
#pragma unroll
      for (int q = 0; q < 4; q++) {
        unsigned short hh = f2bf(vv[q]);
        float r1 = vv[q] - bf2f(hh);
        unsigned short ll = f2bf(r1);
        float r2 = r1 - bf2f(ll);
        hp[q] = hh; lp[q] = ll; l2p[q] = f2bf(r2);
      }
      *(ushort4*)(eselh + i4) = h;
      *(ushort4*)(esell + i4) = l;
      *(ushort4*)(esell2 + i4) = l2;
    }
    return;
  }
  const float* src;
  unsigned short* dst;
  int R, C, r0, c0, e;
  if (bid < 512) {
    e = bid >> 4; int sub = bid & 15;
    R = DD; C = HH; r0 = (sub >> 1) * 64; c0 = (sub & 1) * 64;
    src = keys; dst = keysT;
  } else {
    bid -= 512;
    e = bid >> 4; int sub = bid & 15;
    R = HH; C = DD; r0 = (sub & 1) * 64; c0 = (sub >> 1) * 64;
    src = values; dst = valuesT;
  }
  const int t = threadIdx.x;
  const int rl = t >> 2, cq = (t & 3) * 16;
  const float* s0 = src + ((size_t)e * R + r0 + rl) * C + c0 + cq;
#pragma unroll
  for (int i = 0; i < 4; i++) *(float4*)&tile[rl][cq + 4 * i] = *(const float4*)(s0 + 4 * i);
  __syncthreads();
  unsigned short* d0 = dst + ((size_t)e * C + c0 + rl) * R + r0 + cq;
#pragma unroll
  for (int i = 0; i < 4; i++) {
    ushort4 v;
    v.x = f2bf(tile[cq + 4 * i + 0][rl]);
    v.y = f2bf(tile[cq + 4 * i + 1][rl]);
    v.z = f2bf(tile[cq + 4 * i + 2][rl]);
    v.w = f2bf(tile[cq + 4 * i + 3][rl]);
    *(ushort4*)(d0 + 4 * i) = v;
  }
}

// MFMA router: logits = x @ esel^T computed via exact 3x3 bf16 split (6 terms >= 2^-18).
// Also writes xb = bf16(x). Then top-2 + sigmoid + scatter into per-expert lists.
__global__ __launch_bounds__(128) void router_kernel(
    const float* __restrict__ x,
    const unsigned short* __restrict__ eselh, const unsigned short* __restrict__ esell,
    const unsigned short* __restrict__ esell2,
    unsigned short* __restrict__ xb, int* __restrict__ etok,
    float* __restrict__ ew, int* __restrict__ cur) {
  __shared__ float ls[32][33];
  __shared__ int bcnt[EE], bbase[EE], bcur[EE];
  const int tid = threadIdx.x;
  const int tok0 = blockIdx.x * 32;
  const int wv = tid >> 6, lane = tid & 63;
  const int ll = lane & 15, lh = lane >> 4;
  const int row = tok0 + wv * 16 + ll;

  const float* xr = x + (size_t)row * DD + lh * 8;
  unsigned short* xbr = xb + (size_t)row * DD + lh * 8;
  const unsigned short* b0p = eselh + (size_t)ll * DD + lh * 8;

  f32x4 acc0, acc1;
  acc0[0] = 0.f; acc0[1] = 0.f; acc0[2] = 0.f; acc0[3] = 0.f;
  acc1 = acc0;

  for (int k = 0; k < 16; k++) {
    float4 v0 = *(const float4*)(xr + k * 32);
    float4 v1 = *(const float4*)(xr + k * 32 + 4);
    float vv[8] = {v0.x, v0.y, v0.z, v0.w, v1.x, v1.y, v1.z, v1.w};
    bf16x8 ah, al, al2;
    unsigned short hs[8];
#pragma unroll
    for (int j = 0; j < 8; j++) {
      unsigned short hh = f2bf(vv[j]);
      float r1 = vv[j] - bf2f(hh);
      unsigned short lo = f2bf(r1);
      float r2 = r1 - bf2f(lo);
      hs[j] = hh;
      ah[j] = __builtin_bit_cast(__bf16, hh);
      al[j] = __builtin_bit_cast(__bf16, lo);
      al2[j] = __builtin_bit_cast(__bf16, f2bf(r2));
    }
    *(ushort4*)(xbr + k * 32) = *(ushort4*)&hs[0];
    *(ushort4*)(xbr + k * 32 + 4) = *(ushort4*)&hs[4];

    size_t bo = (size_t)k * 32;
    bf16x8 bh0 = *(const bf16x8*)(b0p + bo);
    bf16x8 bh1 = *(const bf16x8*)(b0p + 16 * DD + bo);
    bf16x8 bl0 = *(const bf16x8*)(esell + (size_t)ll * DD + lh * 8 + bo);
    bf16x8 bl1 = *(const bf16x8*)(esell + (size_t)(ll + 16) * DD + lh * 8 + bo);
    bf16x8 bm0 = *(const bf16x8*)(esell2 + (size_t)ll * DD + lh * 8 + bo);
    bf16x8 bm1 = *(const bf16x8*)(esell2 + (size_t)(ll + 16) * DD + lh * 8 + bo);

    acc0 = __builtin_amdgcn_mfma_f32_16x16x32_bf16(ah, bh0, acc0, 0, 0, 0);
    acc0 = __builtin_amdgcn_mfma_f32_16x16x32_bf16(ah, bl0, acc0, 0, 0, 0);
    acc0 = __builtin_amdgcn_mfma_f32_16x16x32_bf16(al, bh0, acc0, 0, 0, 0);
    acc0 = __builtin_amdgcn_mfma_f32_16x16x32_bf16(ah, bm0, acc0, 0, 0, 0);
    acc0 = __builtin_amdgcn_mfma_f32_16x16x32_bf16(al, bl0, acc0, 0, 0, 0);
    acc0 = __builtin_amdgcn_mfma_f32_16x16x32_bf16(al2, bh0, acc0, 0, 0, 0);

    acc1 = __builtin_amdgcn_mfma_f32_16x16x32_bf16(ah, bh1, acc1, 0, 0, 0);
    acc1 = __builtin_amdgcn_mfma_f32_16x16x32_bf16(ah, bl1, acc1, 0, 0, 0);
    acc1 = __builtin_amdgcn_mfma_f32_16x16x32_bf16(al, bh1, acc1, 0, 0, 0);
    acc1 = __builtin_amdgcn_mfma_f32_16x16x32_bf16(ah, bm1, acc1, 0, 0, 0);
    acc1 = __builtin_amdgcn_mfma_f32_16x16x32_bf16(al, bl1, acc1, 0, 0, 0);
    acc1 = __builtin_amdgcn_mfma_f32_16x16x32_bf16(al2, bh1, acc1, 0, 0, 0);
  }

#pragma unroll
  for (int r = 0; r < 4; r++) {
    ls[wv * 16 + lh * 4 + r][ll] = acc0[r];
    ls[wv * 16 + lh * 4 + r][16 + ll] = acc1[r];
  }
  if (tid < EE) bcnt[tid] = 0;
  __syncthreads();

  int i0 = 0, i1 = 0;
  float w0 = 0.f, w1 = 0.f;
  if (tid < 32) {
    float m0 = -3.4e38f;
#pragma unroll
    for (int e2 = 0; e2 < EE; e2++) {
      float v = ls[tid][e2];
      if (v > m0) { m0 = v; i0 = e2; }
    }
    float m1 = -3.4e38f;
    i1 = (i0 == 0) ? 1 : 0;
#pragma unroll
    for (int e2 = 0; e2 < EE; e2++) {
      float v = ls[tid][e2];
      if (e2 != i0 && v > m1) { m1 = v; i1 = e2; }
    }
    w0 = 1.f / (1.f + expf(-m0));
    w1 = 1.f / (1.f + expf(-m1));
    atomicAdd(&bcnt[i0], 1);
    atomicAdd(&bcnt[i1], 1);
  }
  __syncthreads();
  if (tid < EE) { bbase[tid] = atomicAdd(&cur[tid], bcnt[tid]); bcur[tid] = 0; }
  __syncthreads();
  if (tid < 32) {
    int t = tok0 + tid;
    int p0 = bbase[i0] + atomicAdd(&bcur[i0], 1);
    etok[(size_t)i0 * TT + p0] = t;              // slot 0
    ew[(size_t)i0 * TT + p0] = w0;
    int p1 = bbase[i1] + atomicAdd(&bcur[i1], 1);
    etok[(size_t)i1 * TT + p1] = t | (1 << 20);  // slot 1
    ew[(size_t)i1 * TT + p1] = w1;
  }
}

// Grouped expert GEMM, 8 waves, LDS-staged B (double buffer + XOR swizzle).
// Per (expert, 64-token tile): h=relu(Xg@K_e); ybuf[slot][tok] = w*(h@V_e) (plain stores).
__global__ __launch_bounds__(512) void moe_gemm_kernel(
    const unsigned short* __restrict__ xb,
    const unsigned short* __restrict__ keysT,
    const unsigned short* __restrict__ valuesT,
    const int* __restrict__ cur,
    const int* __restrict__ etok,
    const float* __restrict__ ew,
    float* __restrict__ ybuf) {
  const int e = blockIdx.x;
  const int cnt = cur[e];
  const int base = blockIdx.y * 64;
  if (base >= cnt) return;

  __shared__ unsigned short stage_buf[2][8192];
  __shared__ unsigned short h_swz[8192];
  __shared__ int tok_s[64];
  __shared__ int srow_s[64];
  __shared__ float w_s[64];

  const int tid = threadIdx.x;
  const int lane = tid & 63;
  const int wv = tid >> 6;
  const int wm = wv & 3;
  const int wn = wv >> 2;
  const int ll = lane & 15, lh = lane >> 4;

  const unsigned short* kT = keysT + (size_t)e * HH * DD;
  const unsigned short* vT = valuesT + (size_t)e * DD * HH;

  auto stage_b1 = [&](int c, int b) {
#pragma unroll
    for (int i = 0; i < 2; i++) {
      int P = (i * 512 + tid) * 16;
      int n = P >> 7;
      int q = P & 127;
      const char* g = (const char*)(kT + (size_t)n * DD + c * 64) + (q ^ ((n & 7) << 4));
      char* l = (char*)stage_buf[b] + (i * 512 + (tid & ~63)) * 16;
      GLD16(g, l);
    }
  };
  auto stage_b2 = [&](int c, int b) {
#pragma unroll
    for (int i = 0; i < 2; i++) {
      int P = (i * 512 + tid) * 16;
      int r = P >> 8;
      int q = P & 255;
      const char* g = (const char*)(vT + (size_t)(c * 64 + r) * HH) + (q ^ ((r & 7) << 4));
      char* l = (char*)stage_buf[b] + (i * 512 + (tid & ~63)) * 16;
      GLD16(g, l);
    }
  };

  stage_b1(0, 0);
  if (tid < 64) {
    int i = base + tid;
    if (i < cnt) {
      int v = etok[(size_t)e * TT + i];
      int t = v & 0xFFFFF;
      tok_s[tid] = t;
      srow_s[tid] = (v >> 20) * (TT + 1) + t;
      w_s[tid] = ew[(size_t)e * TT + i];
    } else {
      tok_s[tid] = etok[(size_t)e * TT + base] & 0xFFFFF;
      srow_s[tid] = TT;  // dump row
      w_s[tid] = 0.f;
    }
  }
  __syncthreads();

  const unsigned short* ap = xb + (size_t)tok_s[wm * 16 + ll] * DD;

  f32x4 acc[4];
#pragma unroll
  for (int n = 0; n < 4; n++) { acc[n][0] = 0.f; acc[n][1] = 0.f; acc[n][2] = 0.f; acc[n][3] = 0.f; }

  for (int c = 0; c < 8; c++) {
    if (c < 7) stage_b1(c + 1, (c + 1) & 1);
    else       stage_b2(0, 0);
    const char* sb = (const char*)stage_buf[c & 1];
#pragma unroll
    for (int kkl = 0; kkl < 2; kkl++) {
      bf16x8 af = *(const bf16x8*)(ap + c * 64 + kkl * 32 + lh * 8);
#pragma unroll
      for (int nt = 0; nt < 4; nt++) {
        int n = wn * 64 + nt * 16 + ll;
        int boff = n * 128 + ((kkl * 64 + lh * 16) ^ ((n & 7) << 4));
        bf16x8 bfr = *(const bf16x8*)(sb + boff);
        acc[nt] = __builtin_amdgcn_mfma_f32_16x16x32_bf16(af, bfr, acc[nt], 0, 0, 0);
      }
    }
    __syncthreads();
  }

#pragma unroll
  for (int nt = 0; nt < 4; nt++) {
#pragma unroll
    for (int r = 0; r < 4; r++) {
      int row = wm * 16 + lh * 4 + r;
      int col = wn * 64 + nt * 16 + ll;
      int off = row * 256 + ((col * 2) ^ ((row & 7) << 4));
      *(unsigned short*)((char*)h_swz + off) = f2bf(fmaxf(acc[nt][r], 0.f));
    }
  }
  __syncthreads();

  bf16x8 a2[4];
#pragma unroll
  for (int kk = 0; kk < 4; kk++) {
    int row = wm * 16 + ll;
    int off = row * 256 + ((kk * 64 + lh * 16) ^ ((row & 7) << 4));
    a2[kk] = *(const bf16x8*)((const char*)h_swz + off);
  }

  float wr[4];
  int sr[4];
#pragma unroll
  for (int r = 0; r < 4; r++) {
    int row = wm * 16 + lh * 4 + r;
    wr[r] = w_s[row];
    sr[r] = srow_s[row];
  }

  for (int c = 0; c < 8; c++) {
    if (c < 7) stage_b2(c + 1, (c + 1) & 1);
    const char* sb = (const char*)stage_buf[c & 1];
#pragma unroll
    for (int ntl = 0; ntl < 2; ntl++) {
      f32x4 c2;
      c2[0] = 0.f; c2[1] = 0.f; c2[2] = 0.f; c2[3] = 0.f;
#pragma unroll
      for (int kk = 0; kk < 4; kk++) {
        int r = wn * 32 + ntl * 16 + ll;
        int boff = r * 256 + ((kk * 64 + lh * 16) ^ ((r & 7) << 4));
        bf16x8 bfr = *(const bf16x8*)(sb + boff);
        c2 = __builtin_amdgcn_mfma_f32_16x16x32_bf16(a2[kk], bfr, c2, 0, 0, 0);
      }
      int col = c * 64 + wn * 32 + ntl * 16 + ll;
#pragma unroll
      for (int r = 0; r < 4; r++) {
        ybuf[(size_t)sr[r] * DD + col] = c2[r] * wr[r];
      }
    }
    __syncthreads();
  }
}

// out[t][d] = ybuf[0][t][d] + ybuf[1][t][d]
__global__ __launch_bounds__(256) void combine_kernel(const float* __restrict__ ybuf,
                                                      float* __restrict__ out) {
  size_t i = ((size_t)blockIdx.x * 256 + threadIdx.x) * 4;
  float4 a = *(const float4*)(ybuf + i);
  float4 b = *(const float4*)(ybuf + (size_t)(TT + 1) * DD + i);
  float4 o;
  o.x = a.x + b.x; o.y = a.y + b.y; o.z = a.z + b.z; o.w = a.w + b.w;
  *(float4*)(out + i) = o;
}

extern "C" void kernel_launch(void* const* d_in, const int* in_sizes, int n_in,
                              void* d_out, int out_size, void* d_ws, size_t ws_size,
                              hipStream_t stream) {
  const float* x = (const float*)d_in[0];
  const float* esel = (const float*)d_in[1];
  const float* keys = (const float*)d_in[2];
  const float* values = (const float*)d_in[3];
  float* out = (float*)d_out;

  char* p = (char*)d_ws;
  unsigned short* xb = (unsigned short*)p;      p += (size_t)TT * DD * 2;
  unsigned short* keysT = (unsigned short*)p;   p += (size_t)EE * DD * HH * 2;
  unsigned short* valuesT = (unsigned short*)p; p += (size_t)EE * DD * HH * 2;
  unsigned short* eselh = (unsigned short*)p;   p += (size_t)EE * DD * 2;
  unsigned short* esell = (unsigned short*)p;   p += (size_t)EE * DD * 2;
  unsigned short* esell2 = (unsigned short*)p;  p += (size_t)EE * DD * 2;
  int* cur = (int*)p;                           p += 256;
  int* etok = (int*)p;                          p += (size_t)EE * TT * 4;
  float* ew = (float*)p;                        p += (size_t)EE * TT * 4;
  float* ybuf = (float*)p;                      p += (size_t)2 * (TT + 1) * DD * 4;

  hipMemsetAsync(cur, 0, EE * 4, stream);
  convert_kernel<<<1025, 256, 0, stream>>>(keys, values, esel, keysT, valuesT,
                                           eselh, esell, esell2);
  router_kernel<<<TT / 32, 128, 0, stream>>>(x, eselh, esell, esell2, xb, etok, ew, cur);
  moe_gemm_kernel<<<dim3(EE, TT / 64), 512, 0, stream>>>(xb, keysT, valuesT, cur, etok, ew, ybuf);
  combine_kernel<<<(TT * DD / 4) / 256, 256, 0, stream>>>(ybuf, out);
}